// Round 1
// baseline (300.901 us; speedup 1.0000x reference)
//
#include <hip/hip_runtime.h>
#include <math.h>

#define NW   12
#define NL   2
#define DIM  4096          // 2^NW
#define TPB  256
#define NPAIR (DIM/2)      // 2048
#define PPT  (NPAIR/TPB)   // 8 pairs per thread
#define APT  (DIM/TPB)     // 16 amps per thread

// One block = one sample. State lives in LDS as separate re/im float arrays.
// Wire w <-> bit position (NW-1-w) (PennyLane MSB convention).
__global__ __launch_bounds__(TPB) void qsim_kernel(
    const float* __restrict__ x,        // (B, NW)
    const float* __restrict__ params,   // (NL, NW, 3)
    const float* __restrict__ head_w,   // (1, NW)
    const float* __restrict__ head_b,   // (1,)
    float* __restrict__ out)            // (B,)
{
    __shared__ float re[DIM];
    __shared__ float im[DIM];
    __shared__ float gmat[NL * NW * 8]; // fused U = RY*RX*RZ per (l,w): 8 floats
    __shared__ float wsum[TPB / 64];

    const int tid = threadIdx.x;
    const int b   = blockIdx.x;

    // ---- init state + precompute fused shared gates (before one barrier) ----
    for (int k = tid; k < DIM; k += TPB) { re[k] = 0.f; im[k] = 0.f; }
    if (tid == 0) re[0] = 1.f;

    if (tid < NL * NW) {
        const float* p = params + tid * 3;
        float s1, c1, s2, c2, s3, c3;
        sincosf(0.5f * p[0], &s1, &c1);   // RZ(t1)
        sincosf(0.5f * p[1], &s2, &c2);   // RX(t2)
        sincosf(0.5f * p[2], &s3, &c3);   // RY(t3)
        // U = RY(t3) * RX(t2) * RZ(t1)
        float* g = gmat + tid * 8;
        g[0] =  c3*c2*c1 + s3*s2*s1;      // U00.re
        g[1] =  s3*s2*c1 - c3*c2*s1;      // U00.im
        g[2] =  c3*s2*s1 - s3*c2*c1;      // U01.re
        g[3] = -(c3*s2*c1 + s3*c2*s1);    // U01.im
        g[4] =  s3*c2*c1 - c3*s2*s1;      // U10.re
        g[5] = -(s3*c2*s1 + c3*s2*c1);    // U10.im
        g[6] =  s3*s2*s1 + c3*c2*c1;      // U11.re
        g[7] =  c3*c2*s1 - s3*s2*c1;      // U11.im
    }
    __syncthreads();

    // ---- feature encoding: per-sample RY(x[b][w]) on each wire ----
    for (int w = 0; w < NW; ++w) {
        float s, c;
        sincosf(0.5f * x[b * NW + w], &s, &c);
        const int D = 1 << (NW - 1 - w);
        #pragma unroll
        for (int k = 0; k < PPT; ++k) {
            int p  = tid + k * TPB;
            int i0 = ((p & ~(D - 1)) << 1) | (p & (D - 1));
            int i1 = i0 + D;
            float a0r = re[i0], a0i = im[i0];
            float a1r = re[i1], a1i = im[i1];
            re[i0] = c * a0r - s * a1r;  im[i0] = c * a0i - s * a1i;
            re[i1] = s * a0r + c * a1r;  im[i1] = s * a0i + c * a1i;
        }
        __syncthreads();
    }

    // ---- variational layers ----
    for (int l = 0; l < NL; ++l) {
        for (int w = 0; w < NW; ++w) {
            const float* g = gmat + (l * NW + w) * 8;
            float g00r = g[0], g00i = g[1], g01r = g[2], g01i = g[3];
            float g10r = g[4], g10i = g[5], g11r = g[6], g11i = g[7];
            const int D = 1 << (NW - 1 - w);
            #pragma unroll
            for (int k = 0; k < PPT; ++k) {
                int p  = tid + k * TPB;
                int i0 = ((p & ~(D - 1)) << 1) | (p & (D - 1));
                int i1 = i0 + D;
                float a0r = re[i0], a0i = im[i0];
                float a1r = re[i1], a1i = im[i1];
                re[i0] = g00r*a0r - g00i*a0i + g01r*a1r - g01i*a1i;
                im[i0] = g00r*a0i + g00i*a0r + g01r*a1i + g01i*a1r;
                re[i1] = g10r*a0r - g10i*a0i + g11r*a1r - g11i*a1i;
                im[i1] = g10r*a0i + g10i*a0r + g11r*a1i + g11i*a1r;
            }
            __syncthreads();
        }
        // CNOT chain (w=0..NW-2) fused into one permutation pass.
        // s_final[i] = s[src(i)], src(i) = map_0(map_1(...map_{NW-2}(i)...)),
        // map_w(j) = j ^ (bit_{NW-1-w}(j) << (NW-2-w)).
        float tr[APT], ti[APT];
        #pragma unroll
        for (int k = 0; k < APT; ++k) {
            int i = tid + k * TPB;
            int j = i;
            #pragma unroll
            for (int w = NW - 2; w >= 0; --w)
                j ^= ((j >> (NW - 1 - w)) & 1) << (NW - 2 - w);
            tr[k] = re[j];  ti[k] = im[j];
        }
        __syncthreads();
        #pragma unroll
        for (int k = 0; k < APT; ++k) {
            int i = tid + k * TPB;
            re[i] = tr[k];  im[i] = ti[k];
        }
        __syncthreads();
    }

    // ---- readout: out[b] = sum_i |amp_i|^2 * (sum_w sign_w(i)*hw[w]) + hb ----
    float hw[NW];
    #pragma unroll
    for (int w = 0; w < NW; ++w) hw[w] = head_w[w];

    float local = 0.f;
    #pragma unroll
    for (int k = 0; k < APT; ++k) {
        int i = tid + k * TPB;
        float pr = re[i], pi = im[i];
        float prob = pr * pr + pi * pi;
        float coef = 0.f;
        #pragma unroll
        for (int w = 0; w < NW; ++w)
            coef += ((i >> (NW - 1 - w)) & 1) ? -hw[w] : hw[w];
        local += prob * coef;
    }
    // wave (64-lane) reduction, then cross-wave via LDS
    #pragma unroll
    for (int off = 32; off > 0; off >>= 1)
        local += __shfl_down(local, off, 64);
    if ((tid & 63) == 0) wsum[tid >> 6] = local;
    __syncthreads();
    if (tid == 0)
        out[b] = wsum[0] + wsum[1] + wsum[2] + wsum[3] + head_b[0];
}

extern "C" void kernel_launch(void* const* d_in, const int* in_sizes, int n_in,
                              void* d_out, int out_size, void* d_ws, size_t ws_size,
                              hipStream_t stream) {
    const float* x      = (const float*)d_in[0];
    const float* params = (const float*)d_in[1];
    const float* head_w = (const float*)d_in[2];
    const float* head_b = (const float*)d_in[3];
    float* out = (float*)d_out;
    const int B = in_sizes[0] / NW;   // 4096
    qsim_kernel<<<B, TPB, 0, stream>>>(x, params, head_w, head_b, out);
}

// Round 2
// 206.528 us; speedup vs baseline: 1.4570x; 1.4570x over previous
//
#include <hip/hip_runtime.h>
#include <math.h>

#define NW 12
#define NL 2
#define DIM 4096
#define TPB 256

// Bank-conflict-free bijective slot map. Keeps bit 0 (so amp pairs 2m,2m+1
// stay contiguous for float4 access); XOR-folds bits 5..11 into bits 1..4.
__device__ __forceinline__ int slot_of(int i) {
    return i ^ ((((i >> 5) ^ (i >> 9)) & 15) << 1);
}

// Prefix-XOR (inverse Gray code): px(j) ^ (px(j)>>1) == j.
__device__ __forceinline__ int px12(int j) {
    j ^= j >> 1; j ^= j >> 2; j ^= j >> 4; j ^= j >> 8;
    return j;
}

// Apply shared complex 2x2 gate to register subcube on local bit mask M.
#define APPLY_G(gp, M) do { \
    const float* _g = (gp); \
    float g00r=_g[0], g00i=_g[1], g01r=_g[2], g01i=_g[3]; \
    float g10r=_g[4], g10i=_g[5], g11r=_g[6], g11i=_g[7]; \
    _Pragma("unroll") \
    for (int _k = 0; _k < 16; ++_k) { \
        if (_k & (M)) continue; \
        int _k1 = _k | (M); \
        float a0r=ar[_k], a0i=ai[_k], a1r=ar[_k1], a1i=ai[_k1]; \
        ar[_k]  = g00r*a0r - g00i*a0i + g01r*a1r - g01i*a1i; \
        ai[_k]  = g00r*a0i + g00i*a0r + g01r*a1i + g01i*a1r; \
        ar[_k1] = g10r*a0r - g10i*a0i + g11r*a1r - g11i*a1i; \
        ai[_k1] = g10r*a0i + g10i*a0r + g11r*a1i + g11i*a1r; \
    } \
} while (0)

__global__ __launch_bounds__(TPB, 4) void qsim_kernel(
    const float* __restrict__ x,        // (B, NW)
    const float* __restrict__ params,   // (NL, NW, 3)
    const float* __restrict__ head_w,   // (1, NW)
    const float* __restrict__ head_b,   // (1,)
    float* __restrict__ out)            // (B,)
{
    __shared__ float4 st4[DIM / 2];     // state, swizzled float2 slots
    __shared__ float gm[NL * NW * 8];   // fused U = RY*RX*RZ per (l,w)
    __shared__ float cs[NW], sn[NW];    // encoding cos/sin per wire
    __shared__ float T1[64], T2[64];    // readout sign-weighted tables
    __shared__ float wsum[TPB / 64];
    float2* st = (float2*)st4;

    const int t = threadIdx.x;
    const int b = blockIdx.x;

    // ---------------- setup (disjoint thread ranges) ----------------
    if (t < NL * NW) {
        const float* p = params + t * 3;
        float s1, c1, s2, c2, s3, c3;
        sincosf(0.5f * p[0], &s1, &c1);   // RZ
        sincosf(0.5f * p[1], &s2, &c2);   // RX
        sincosf(0.5f * p[2], &s3, &c3);   // RY
        float* g = gm + t * 8;            // U = RY*RX*RZ
        g[0] =  c3*c2*c1 + s3*s2*s1;
        g[1] =  s3*s2*c1 - c3*c2*s1;
        g[2] =  c3*s2*s1 - s3*c2*c1;
        g[3] = -(c3*s2*c1 + s3*c2*s1);
        g[4] =  s3*c2*c1 - c3*s2*s1;
        g[5] = -(s3*c2*s1 + c3*s2*c1);
        g[6] =  s3*s2*s1 + c3*c2*c1;
        g[7] =  c3*c2*s1 - s3*s2*c1;
    } else if (t >= 32 && t < 32 + NW) {
        int w = t - 32;
        float s, c; sincosf(0.5f * x[b * NW + w], &s, &c);
        cs[w] = c; sn[w] = s;
    } else if (t >= 64 && t < 128) {
        int m = t - 64;               // bits 0..5 of final index -> wires 11..6
        float v = 0.f;
        #pragma unroll
        for (int w = 6; w < 12; ++w)
            v += ((m >> (11 - w)) & 1) ? -head_w[w] : head_w[w];
        T1[m] = v;
    } else if (t >= 128 && t < 192) {
        int m = t - 128;              // bits 6..11 of final index -> wires 5..0
        float v = 0.f;
        #pragma unroll
        for (int w = 0; w < 6; ++w)
            v += ((m >> (5 - w)) & 1) ? -head_w[w] : head_w[w];
        T2[m] = v;
    }
    __syncthreads();

    float ar[16], ai[16];

    // ---- P1: build post-encoding state directly + L1 gates on wires 8..11,
    //          write A-subcube (16 consecutive amps) via float4 ----
    {
        float P = 1.f;                        // wires 0..7 <-> bits 11..4 = t
        #pragma unroll
        for (int w = 0; w < 8; ++w)
            P *= ((t >> (7 - w)) & 1) ? sn[w] : cs[w];
        float c8 = cs[8], s8 = sn[8], c9 = cs[9],  s9 = sn[9];
        float c10 = cs[10], s10 = sn[10], c11 = cs[11], s11 = sn[11];
        #pragma unroll
        for (int k = 0; k < 16; ++k) {
            float r = P;
            r *= (k & 8) ? s8  : c8;          // wire 8  <-> bit 3
            r *= (k & 4) ? s9  : c9;
            r *= (k & 2) ? s10 : c10;
            r *= (k & 1) ? s11 : c11;         // wire 11 <-> bit 0
            ar[k] = r; ai[k] = 0.f;
        }
        APPLY_G(gm + (0 * NW + 8)  * 8, 8);
        APPLY_G(gm + (0 * NW + 9)  * 8, 4);
        APPLY_G(gm + (0 * NW + 10) * 8, 2);
        APPLY_G(gm + (0 * NW + 11) * 8, 1);
        #pragma unroll
        for (int m = 0; m < 8; ++m) {
            int i = t * 16 + 2 * m;
            st4[slot_of(i) >> 1] =
                make_float4(ar[2*m], ai[2*m], ar[2*m+1], ai[2*m+1]);
        }
    }
    __syncthreads();

    // ---- P2: L1 gates on wires 4..7 (bits 7..4) ----
    {
        int base = (t & 15) | ((t >> 4) << 8);
        #pragma unroll
        for (int j = 0; j < 16; ++j) {
            float2 v = st[slot_of(base | (j << 4))];
            ar[j] = v.x; ai[j] = v.y;
        }
        APPLY_G(gm + (0 * NW + 4) * 8, 8);
        APPLY_G(gm + (0 * NW + 5) * 8, 4);
        APPLY_G(gm + (0 * NW + 6) * 8, 2);
        APPLY_G(gm + (0 * NW + 7) * 8, 1);
        #pragma unroll
        for (int j = 0; j < 16; ++j)
            st[slot_of(base | (j << 4))] = make_float2(ar[j], ai[j]);
    }
    __syncthreads();

    // ---- P3: L1 gates on wires 0..3 (bits 11..8), CNOT chain folded into
    //          write addresses: dst = prefix-xor(src) ----
    {
        #pragma unroll
        for (int j = 0; j < 16; ++j) {
            float2 v = st[slot_of(t | (j << 8))];
            ar[j] = v.x; ai[j] = v.y;
        }
        APPLY_G(gm + (0 * NW + 0) * 8, 8);
        APPLY_G(gm + (0 * NW + 1) * 8, 4);
        APPLY_G(gm + (0 * NW + 2) * 8, 2);
        APPLY_G(gm + (0 * NW + 3) * 8, 1);
        __syncthreads();                       // all reads done before scatter
        int pt = px12(t);
        #pragma unroll
        for (int j = 0; j < 16; ++j) {
            int d = pt ^ px12(j << 8);         // px is GF(2)-linear
            st[slot_of(d)] = make_float2(ar[j], ai[j]);
        }
    }
    __syncthreads();

    // ---- P4: L2 gates on wires 8..11 (A-subcube, float4) ----
    {
        #pragma unroll
        for (int m = 0; m < 8; ++m) {
            float4 v = st4[slot_of(t * 16 + 2 * m) >> 1];
            ar[2*m] = v.x; ai[2*m] = v.y; ar[2*m+1] = v.z; ai[2*m+1] = v.w;
        }
        APPLY_G(gm + (1 * NW + 8)  * 8, 8);
        APPLY_G(gm + (1 * NW + 9)  * 8, 4);
        APPLY_G(gm + (1 * NW + 10) * 8, 2);
        APPLY_G(gm + (1 * NW + 11) * 8, 1);
        #pragma unroll
        for (int m = 0; m < 8; ++m)
            st4[slot_of(t * 16 + 2 * m) >> 1] =
                make_float4(ar[2*m], ai[2*m], ar[2*m+1], ai[2*m+1]);
    }
    __syncthreads();

    // ---- P5: L2 gates on wires 4..7 ----
    {
        int base = (t & 15) | ((t >> 4) << 8);
        #pragma unroll
        for (int j = 0; j < 16; ++j) {
            float2 v = st[slot_of(base | (j << 4))];
            ar[j] = v.x; ai[j] = v.y;
        }
        APPLY_G(gm + (1 * NW + 4) * 8, 8);
        APPLY_G(gm + (1 * NW + 5) * 8, 4);
        APPLY_G(gm + (1 * NW + 6) * 8, 2);
        APPLY_G(gm + (1 * NW + 7) * 8, 1);
        #pragma unroll
        for (int j = 0; j < 16; ++j)
            st[slot_of(base | (j << 4))] = make_float2(ar[j], ai[j]);
    }
    __syncthreads();

    // ---- P6: L2 gates on wires 0..3 + CNOT2 + readout (no write-back) ----
    float local = 0.f;
    {
        #pragma unroll
        for (int j = 0; j < 16; ++j) {
            float2 v = st[slot_of(t | (j << 8))];
            ar[j] = v.x; ai[j] = v.y;
        }
        APPLY_G(gm + (1 * NW + 0) * 8, 8);
        APPLY_G(gm + (1 * NW + 1) * 8, 4);
        APPLY_G(gm + (1 * NW + 2) * 8, 2);
        APPLY_G(gm + (1 * NW + 3) * 8, 1);
        int pt = px12(t);
        #pragma unroll
        for (int j = 0; j < 16; ++j) {
            int d = pt ^ px12(j << 8);         // final basis index after CNOT2
            float pr = ar[j] * ar[j] + ai[j] * ai[j];
            local += pr * (T1[d & 63] + T2[d >> 6]);
        }
    }

    // ---- block reduction ----
    #pragma unroll
    for (int off = 32; off > 0; off >>= 1)
        local += __shfl_down(local, off, 64);
    if ((t & 63) == 0) wsum[t >> 6] = local;
    __syncthreads();
    if (t == 0)
        out[b] = wsum[0] + wsum[1] + wsum[2] + wsum[3] + head_b[0];
}

extern "C" void kernel_launch(void* const* d_in, const int* in_sizes, int n_in,
                              void* d_out, int out_size, void* d_ws, size_t ws_size,
                              hipStream_t stream) {
    const float* x      = (const float*)d_in[0];
    const float* params = (const float*)d_in[1];
    const float* head_w = (const float*)d_in[2];
    const float* head_b = (const float*)d_in[3];
    float* out = (float*)d_out;
    const int B = in_sizes[0] / NW;   // 4096
    qsim_kernel<<<B, TPB, 0, stream>>>(x, params, head_w, head_b, out);
}

// Round 3
// 143.839 us; speedup vs baseline: 2.0919x; 1.4358x over previous
//
#include <hip/hip_runtime.h>
#include <math.h>

#define NW 12
#define NL 2
#define DIM 4096
#define TPB 256

// Bank-conflict-reducing bijective slot map. Keeps bit 0 (float4 pairs stay
// contiguous); XOR-folds bits 5..8 ^ 9..12 into bits 1..4.
__device__ __forceinline__ int slot_of(int i) {
    return i ^ ((((i >> 5) ^ (i >> 9)) & 15) << 1);
}

// Prefix-XOR (inverse Gray code): px(j) ^ (px(j)>>1) == j. GF(2)-linear.
__device__ __forceinline__ int px12(int j) {
    j ^= j >> 1; j ^= j >> 2; j ^= j >> 4; j ^= j >> 8;
    return j;
}

#define FOR16(X) X(0) X(1) X(2) X(3) X(4) X(5) X(6) X(7) \
                 X(8) X(9) X(10) X(11) X(12) X(13) X(14) X(15)

// ---- fully scalarized 16-amp subcube: named regs r0..r15 (re), u0..u15 (im)
#define LOADG(gp) do { const float* _g = (gp); \
    g00r=_g[0]; g00i=_g[1]; g01r=_g[2]; g01i=_g[3]; \
    g10r=_g[4]; g10i=_g[5]; g11r=_g[6]; g11i=_g[7]; } while (0)

#define GP(A, B) do { \
    float _ar=r##A, _ai=u##A, _br=r##B, _bi=u##B; \
    r##A = g00r*_ar - g00i*_ai + g01r*_br - g01i*_bi; \
    u##A = g00r*_ai + g00i*_ar + g01r*_bi + g01i*_br; \
    r##B = g10r*_ar - g10i*_ai + g11r*_br - g11i*_bi; \
    u##B = g10r*_ai + g10i*_ar + g11r*_bi + g11i*_br; } while (0)

#define APPLY_M8(gp) do { LOADG(gp); GP(0,8); GP(1,9); GP(2,10); GP(3,11); \
                          GP(4,12); GP(5,13); GP(6,14); GP(7,15); } while (0)
#define APPLY_M4(gp) do { LOADG(gp); GP(0,4); GP(1,5); GP(2,6); GP(3,7); \
                          GP(8,12); GP(9,13); GP(10,14); GP(11,15); } while (0)
#define APPLY_M2(gp) do { LOADG(gp); GP(0,2); GP(1,3); GP(4,6); GP(5,7); \
                          GP(8,10); GP(9,11); GP(12,14); GP(13,15); } while (0)
#define APPLY_M1(gp) do { LOADG(gp); GP(0,1); GP(2,3); GP(4,5); GP(6,7); \
                          GP(8,9); GP(10,11); GP(12,13); GP(14,15); } while (0)

__global__ __launch_bounds__(TPB) void qsim_kernel(
    const float* __restrict__ x,        // (B, NW)
    const float* __restrict__ params,   // (NL, NW, 3)
    const float* __restrict__ head_w,   // (1, NW)
    const float* __restrict__ head_b,   // (1,)
    float* __restrict__ out)            // (B,)
{
    __shared__ float4 st4[DIM / 2];     // state, swizzled float2 slots
    __shared__ float gm[NL * NW * 8];   // fused U = RY*RX*RZ per (l,w)
    __shared__ float cs[NW], sn[NW];    // encoding cos/sin per wire
    __shared__ float T1[64], T2[64];    // readout sign-weighted tables
    __shared__ float wsum[TPB / 64];
    float2* st = (float2*)st4;

    const int t = threadIdx.x;
    const int b = blockIdx.x;

    // ---------------- setup (disjoint thread ranges) ----------------
    if (t < NL * NW) {
        const float* p = params + t * 3;
        float s1, c1, s2, c2, s3, c3;
        sincosf(0.5f * p[0], &s1, &c1);   // RZ
        sincosf(0.5f * p[1], &s2, &c2);   // RX
        sincosf(0.5f * p[2], &s3, &c3);   // RY
        float* g = gm + t * 8;            // U = RY*RX*RZ
        g[0] =  c3*c2*c1 + s3*s2*s1;
        g[1] =  s3*s2*c1 - c3*c2*s1;
        g[2] =  c3*s2*s1 - s3*c2*c1;
        g[3] = -(c3*s2*c1 + s3*c2*s1);
        g[4] =  s3*c2*c1 - c3*s2*s1;
        g[5] = -(s3*c2*s1 + c3*s2*c1);
        g[6] =  s3*s2*s1 + c3*c2*c1;
        g[7] =  c3*c2*s1 - s3*s2*c1;
    } else if (t >= 32 && t < 32 + NW) {
        int w = t - 32;
        float s, c; sincosf(0.5f * x[b * NW + w], &s, &c);
        cs[w] = c; sn[w] = s;
    } else if (t >= 64 && t < 128) {
        int m = t - 64;               // bits 0..5 of final index -> wires 11..6
        float v = 0.f;
        #pragma unroll
        for (int w = 6; w < 12; ++w)
            v += ((m >> (11 - w)) & 1) ? -head_w[w] : head_w[w];
        T1[m] = v;
    } else if (t >= 128 && t < 192) {
        int m = t - 128;              // bits 6..11 of final index -> wires 5..0
        float v = 0.f;
        #pragma unroll
        for (int w = 0; w < 6; ++w)
            v += ((m >> (5 - w)) & 1) ? -head_w[w] : head_w[w];
        T2[m] = v;
    }
    __syncthreads();

    float r0,r1,r2,r3,r4,r5,r6,r7,r8,r9,r10,r11,r12,r13,r14,r15;
    float u0,u1,u2,u3,u4,u5,u6,u7,u8,u9,u10,u11,u12,u13,u14,u15;
    float g00r,g00i,g01r,g01i,g10r,g10i,g11r,g11i;

    // ---- P1: post-encoding state built in registers + L1 wires 8..11,
    //          write A-subcube (16 consecutive amps) via float4 ----
    {
        float P = 1.f;                        // wires 0..7 <-> bits 11..4 = t
        #pragma unroll
        for (int w = 0; w < 8; ++w)
            P *= ((t >> (7 - w)) & 1) ? sn[w] : cs[w];
        float c8 = cs[8],  s8 = sn[8],  c9  = cs[9],  s9  = sn[9];
        float c10 = cs[10], s10 = sn[10], c11 = cs[11], s11 = sn[11];
#define ENC(k) { float _r = P; \
        _r *= ((k)&8) ? s8  : c8;  _r *= ((k)&4) ? s9  : c9; \
        _r *= ((k)&2) ? s10 : c10; _r *= ((k)&1) ? s11 : c11; \
        r##k = _r; u##k = 0.f; }
        FOR16(ENC)
#undef ENC
        APPLY_M8(gm + (0 * NW + 8)  * 8);
        APPLY_M4(gm + (0 * NW + 9)  * 8);
        APPLY_M2(gm + (0 * NW + 10) * 8);
        APPLY_M1(gm + (0 * NW + 11) * 8);
#define ST4(m, A, B) st4[slot_of(t * 16 + 2 * (m)) >> 1] = \
        make_float4(r##A, u##A, r##B, u##B);
        ST4(0,0,1) ST4(1,2,3) ST4(2,4,5) ST4(3,6,7)
        ST4(4,8,9) ST4(5,10,11) ST4(6,12,13) ST4(7,14,15)
#undef ST4
    }
    __syncthreads();

    // ---- P2: L1 wires 4..7 (bits 7..4) ----
    {
        int base = (t & 15) | ((t >> 4) << 8);
#define LD_B(j) { float2 _v = st[slot_of(base | ((j) << 4))]; \
                  r##j = _v.x; u##j = _v.y; }
        FOR16(LD_B)
#undef LD_B
        APPLY_M8(gm + (0 * NW + 4) * 8);
        APPLY_M4(gm + (0 * NW + 5) * 8);
        APPLY_M2(gm + (0 * NW + 6) * 8);
        APPLY_M1(gm + (0 * NW + 7) * 8);
#define ST_B(j) st[slot_of(base | ((j) << 4))] = make_float2(r##j, u##j);
        FOR16(ST_B)
#undef ST_B
    }
    __syncthreads();

    // ---- P3: L1 wires 0..3 (bits 11..8) + CNOT chain folded into
    //          write addresses: dst = prefix-xor(src) ----
    {
#define LD_C(j) { float2 _v = st[slot_of(t | ((j) << 8))]; \
                  r##j = _v.x; u##j = _v.y; }
        FOR16(LD_C)
#undef LD_C
        APPLY_M8(gm + (0 * NW + 0) * 8);
        APPLY_M4(gm + (0 * NW + 1) * 8);
        APPLY_M2(gm + (0 * NW + 2) * 8);
        APPLY_M1(gm + (0 * NW + 3) * 8);
        __syncthreads();                       // all reads done before scatter
        int pt = px12(t);
#define ST_C(j) st[slot_of(pt ^ px12((j) << 8))] = make_float2(r##j, u##j);
        FOR16(ST_C)
#undef ST_C
    }
    __syncthreads();

    // ---- P4: L2 wires 8..11 (A-subcube, float4) ----
    {
#define LD4(m, A, B) { float4 _v = st4[slot_of(t * 16 + 2 * (m)) >> 1]; \
        r##A = _v.x; u##A = _v.y; r##B = _v.z; u##B = _v.w; }
        LD4(0,0,1) LD4(1,2,3) LD4(2,4,5) LD4(3,6,7)
        LD4(4,8,9) LD4(5,10,11) LD4(6,12,13) LD4(7,14,15)
#undef LD4
        APPLY_M8(gm + (1 * NW + 8)  * 8);
        APPLY_M4(gm + (1 * NW + 9)  * 8);
        APPLY_M2(gm + (1 * NW + 10) * 8);
        APPLY_M1(gm + (1 * NW + 11) * 8);
#define ST4(m, A, B) st4[slot_of(t * 16 + 2 * (m)) >> 1] = \
        make_float4(r##A, u##A, r##B, u##B);
        ST4(0,0,1) ST4(1,2,3) ST4(2,4,5) ST4(3,6,7)
        ST4(4,8,9) ST4(5,10,11) ST4(6,12,13) ST4(7,14,15)
#undef ST4
    }
    __syncthreads();

    // ---- P5: L2 wires 4..7 ----
    {
        int base = (t & 15) | ((t >> 4) << 8);
#define LD_B(j) { float2 _v = st[slot_of(base | ((j) << 4))]; \
                  r##j = _v.x; u##j = _v.y; }
        FOR16(LD_B)
#undef LD_B
        APPLY_M8(gm + (1 * NW + 4) * 8);
        APPLY_M4(gm + (1 * NW + 5) * 8);
        APPLY_M2(gm + (1 * NW + 6) * 8);
        APPLY_M1(gm + (1 * NW + 7) * 8);
#define ST_B(j) st[slot_of(base | ((j) << 4))] = make_float2(r##j, u##j);
        FOR16(ST_B)
#undef ST_B
    }
    __syncthreads();

    // ---- P6: L2 wires 0..3 + CNOT2 + readout (no write-back) ----
    float local = 0.f;
    {
#define LD_C(j) { float2 _v = st[slot_of(t | ((j) << 8))]; \
                  r##j = _v.x; u##j = _v.y; }
        FOR16(LD_C)
#undef LD_C
        APPLY_M8(gm + (1 * NW + 0) * 8);
        APPLY_M4(gm + (1 * NW + 1) * 8);
        APPLY_M2(gm + (1 * NW + 2) * 8);
        APPLY_M1(gm + (1 * NW + 3) * 8);
        int pt = px12(t);
#define RD(j) { int _d = pt ^ px12((j) << 8); \
        local += (r##j * r##j + u##j * u##j) * (T1[_d & 63] + T2[_d >> 6]); }
        FOR16(RD)
#undef RD
    }

    // ---- block reduction ----
    #pragma unroll
    for (int off = 32; off > 0; off >>= 1)
        local += __shfl_down(local, off, 64);
    if ((t & 63) == 0) wsum[t >> 6] = local;
    __syncthreads();
    if (t == 0)
        out[b] = wsum[0] + wsum[1] + wsum[2] + wsum[3] + head_b[0];
}

extern "C" void kernel_launch(void* const* d_in, const int* in_sizes, int n_in,
                              void* d_out, int out_size, void* d_ws, size_t ws_size,
                              hipStream_t stream) {
    const float* x      = (const float*)d_in[0];
    const float* params = (const float*)d_in[1];
    const float* head_w = (const float*)d_in[2];
    const float* head_b = (const float*)d_in[3];
    float* out = (float*)d_out;
    const int B = in_sizes[0] / NW;   // 4096
    qsim_kernel<<<B, TPB, 0, stream>>>(x, params, head_w, head_b, out);
}

// Round 7
// 123.566 us; speedup vs baseline: 2.4351x; 1.1641x over previous
//
#include <hip/hip_runtime.h>
#include <math.h>

#define NW 12
#define DIM 4096
#define TPB 256

// Bank-conflict-reducing bijective slot map (XOR-linear involution, fixes bit 0).
__device__ __forceinline__ int slot_of(int i) {
    return i ^ ((((i >> 5) ^ (i >> 9)) & 15) << 1);
}
// Prefix-XOR (inverse Gray code): px12(j) ^ (px12(j)>>1) == j. XOR-linear.
__device__ __forceinline__ int px12(int j) {
    j ^= j >> 1; j ^= j >> 2; j ^= j >> 4; j ^= j >> 8;
    return j;
}
// 4-bit prefix-xor for literals k<16
#define PX4(k) ((k) ^ ((k) >> 1) ^ ((k) >> 2) ^ ((k) >> 3))

#define FOR16(X) X(0) X(1) X(2) X(3) X(4) X(5) X(6) X(7) \
                 X(8) X(9) X(10) X(11) X(12) X(13) X(14) X(15)

// (pr,pi) *= (fr,fi)
__device__ __forceinline__ void cmul(float& pr, float& pi, float fr, float fi) {
    float t0 = pi * fi, t1 = pi * fr;
    pi = fmaf(pr, fi, t1);
    pr = fmaf(pr, fr, -t0);
}

// fused U = RY(p2)*RX(p1)*RZ(p0); row-major complex 2x2 as 8 floats
struct GateU { float g0,g1,g2,g3,g4,g5,g6,g7; };
__device__ __forceinline__ GateU fuse_u(const float* p) {
    float s1,c1,s2,c2,s3,c3;
    sincosf(0.5f * p[0], &s1, &c1);   // RZ
    sincosf(0.5f * p[1], &s2, &c2);   // RX
    sincosf(0.5f * p[2], &s3, &c3);   // RY
    GateU r;
    r.g0 =  c3*c2*c1 + s3*s2*s1;
    r.g1 =  s3*s2*c1 - c3*c2*s1;
    r.g2 =  c3*s2*s1 - s3*c2*c1;
    r.g3 = -(c3*s2*c1 + s3*c2*s1);
    r.g4 =  s3*c2*c1 - c3*s2*s1;
    r.g5 = -(s3*c2*s1 + c3*s2*c1);
    r.g6 =  s3*s2*s1 + c3*c2*c1;
    r.g7 =  c3*c2*s1 - s3*s2*c1;
    return r;
}

// apply complex 2x2 gate (ga = row0, gb = row1) to one amplitude pair
__device__ __forceinline__ void gpair(const float4 ga, const float4 gb,
                                      float& ar, float& ai,
                                      float& br, float& bi) {
    float a0r = ar, a0i = ai, a1r = br, a1i = bi;
    ar = ga.x*a0r - ga.y*a0i + ga.z*a1r - ga.w*a1i;
    ai = ga.x*a0i + ga.y*a0r + ga.z*a1i + ga.w*a1r;
    br = gb.x*a0r - gb.y*a0i + gb.z*a1r - gb.w*a1i;
    bi = gb.x*a0i + gb.y*a0r + gb.z*a1i + gb.w*a1r;
}

// per-pass gate application on the 16-amp register subcube (mask 8/4/2/1)
#define APW8(W) { const float4 ga = gm4[2*(W)], gb = gm4[2*(W)+1]; \
    gpair(ga,gb,r0,u0,r8,u8);     gpair(ga,gb,r1,u1,r9,u9); \
    gpair(ga,gb,r2,u2,r10,u10);   gpair(ga,gb,r3,u3,r11,u11); \
    gpair(ga,gb,r4,u4,r12,u12);   gpair(ga,gb,r5,u5,r13,u13); \
    gpair(ga,gb,r6,u6,r14,u14);   gpair(ga,gb,r7,u7,r15,u15); }

#define APW4(W) { const float4 ga = gm4[2*(W)], gb = gm4[2*(W)+1]; \
    gpair(ga,gb,r0,u0,r4,u4);     gpair(ga,gb,r1,u1,r5,u5); \
    gpair(ga,gb,r2,u2,r6,u6);     gpair(ga,gb,r3,u3,r7,u7); \
    gpair(ga,gb,r8,u8,r12,u12);   gpair(ga,gb,r9,u9,r13,u13); \
    gpair(ga,gb,r10,u10,r14,u14); gpair(ga,gb,r11,u11,r15,u15); }

#define APW2(W) { const float4 ga = gm4[2*(W)], gb = gm4[2*(W)+1]; \
    gpair(ga,gb,r0,u0,r2,u2);     gpair(ga,gb,r1,u1,r3,u3); \
    gpair(ga,gb,r4,u4,r6,u6);     gpair(ga,gb,r5,u5,r7,u7); \
    gpair(ga,gb,r8,u8,r10,u10);   gpair(ga,gb,r9,u9,r11,u11); \
    gpair(ga,gb,r12,u12,r14,u14); gpair(ga,gb,r13,u13,r15,u15); }

#define APW1(W) { const float4 ga = gm4[2*(W)], gb = gm4[2*(W)+1]; \
    gpair(ga,gb,r0,u0,r1,u1);     gpair(ga,gb,r2,u2,r3,u3); \
    gpair(ga,gb,r4,u4,r5,u5);     gpair(ga,gb,r6,u6,r7,u7); \
    gpair(ga,gb,r8,u8,r9,u9);     gpair(ga,gb,r10,u10,r11,u11); \
    gpair(ga,gb,r12,u12,r13,u13); gpair(ga,gb,r14,u14,r15,u15); }

__global__ __launch_bounds__(TPB) void qsim_kernel(
    const float* __restrict__ x,        // (B, NW)
    const float* __restrict__ params,   // (NL, NW, 3)
    const float* __restrict__ head_w,   // (1, NW)
    const float* __restrict__ head_b,   // (1,)
    float* __restrict__ out)            // (B,)
{
    __shared__ float4 st4[DIM / 2];     // state, swizzled float2 slots (16B-aligned)
    __shared__ float2 ab[2 * NW];       // (alpha,beta) per wire: enc+L1 folded
    __shared__ float2 leaf[16];         // product of ab for wires 8..11
    __shared__ float4 gm4[2 * NW];      // L2 fused gates, 2 x float4 each
    __shared__ float T1[64], T2[64];    // readout sign-weighted tables
    __shared__ float wsum[TPB / 64];
    char* stb = (char*)st4;

    const int t = threadIdx.x;
    const int b = blockIdx.x;

    // ---------------- setup phase A (disjoint thread ranges) ----------------
    if (t < NW) {
        // wire t: fused L1 gate folded with encoding RY(x): (alpha,beta)=U*(c,s)
        GateU U = fuse_u(params + t * 3);             // layer 0
        float sx, cx; sincosf(0.5f * x[b * NW + t], &sx, &cx);
        ab[2*t]   = make_float2(U.g0*cx + U.g2*sx, U.g1*cx + U.g3*sx);
        ab[2*t+1] = make_float2(U.g4*cx + U.g6*sx, U.g5*cx + U.g7*sx);
    } else if (t < 2 * NW) {
        int w = t - NW;
        GateU U = fuse_u(params + (NW + w) * 3);      // layer 1
        gm4[2*w]   = make_float4(U.g0, U.g1, U.g2, U.g3);
        gm4[2*w+1] = make_float4(U.g4, U.g5, U.g6, U.g7);
    } else if (t >= 64 && t < 128) {
        int m = t - 64;               // bits 0..5 of final index -> wires 11..6
        float v = 0.f;
        #pragma unroll
        for (int w = 6; w < 12; ++w)
            v += ((m >> (11 - w)) & 1) ? -head_w[w] : head_w[w];
        T1[m] = v;
    } else if (t >= 128 && t < 192) {
        int m = t - 128;              // bits 6..11 of final index -> wires 5..0
        float v = 0.f;
        #pragma unroll
        for (int w = 0; w < 6; ++w)
            v += ((m >> (5 - w)) & 1) ? -head_w[w] : head_w[w];
        T2[m] = v;
    }
    __syncthreads();

    // ---------------- setup phase B: leaf[k] over wires 8..11 ----------------
    if (t < 16) {
        float2 f8 = ab[16 + ((t >> 3) & 1)];
        float2 f9 = ab[18 + ((t >> 2) & 1)];
        float2 fA = ab[20 + ((t >> 1) & 1)];
        float2 fB = ab[22 + (t & 1)];
        float pr = f8.x, pi = f8.y;
        cmul(pr, pi, f9.x, f9.y);
        cmul(pr, pi, fA.x, fA.y);
        cmul(pr, pi, fB.x, fB.y);
        leaf[t] = make_float2(pr, pi);
    }
    __syncthreads();

    float r0,r1,r2,r3,r4,r5,r6,r7,r8,r9,r10,r11,r12,r13,r14,r15;
    float u0,u1,u2,u3,u4,u5,u6,u7,u8,u9,u10,u11,u12,u13,u14,u15;

    // ---- P1: build full post-L1 product state in registers; CNOT1 chain
    //          folded into write addresses (dst = px12(src), XOR-linear) ----
    {
        float2 f0 = ab[(t >> 7) & 1];
        float Pr = f0.x, Pi = f0.y;
        #pragma unroll
        for (int w = 1; w < 8; ++w) {
            float2 g = ab[2 * w + ((t >> (7 - w)) & 1)];
            cmul(Pr, Pi, g.x, g.y);
        }
        const int B1 = slot_of(px12(t << 4)) << 3;    // byte base (runtime)
#define W1(k) { float2 lf = leaf[k]; \
        float i0 = Pi * lf.y, i1 = Pi * lf.x; \
        float re_ = fmaf(Pr, lf.x, -i0), im_ = fmaf(Pr, lf.y, i1); \
        *(float2*)(stb + (B1 ^ (PX4(k) << 3))) = make_float2(re_, im_); }
        FOR16(W1)
#undef W1
    }
    __syncthreads();

    // ---- P2: L2 wires 8..11 on own 16-amp block (float4, in-place) ----
    {
        const int B2 = slot_of(t << 4) << 3;          // 16B-aligned
#define LD4_(m, A, B) { float4 v_ = *(const float4*)(stb + (B2 ^ ((m) << 4))); \
        r##A = v_.x; u##A = v_.y; r##B = v_.z; u##B = v_.w; }
        LD4_(0,0,1) LD4_(1,2,3) LD4_(2,4,5) LD4_(3,6,7)
        LD4_(4,8,9) LD4_(5,10,11) LD4_(6,12,13) LD4_(7,14,15)
#undef LD4_
        APW8(8)
        APW4(9)
        APW2(10)
        APW1(11)
#define ST4_(m, A, B) *(float4*)(stb + (B2 ^ ((m) << 4))) = \
        make_float4(r##A, u##A, r##B, u##B);
        ST4_(0,0,1) ST4_(1,2,3) ST4_(2,4,5) ST4_(3,6,7)
        ST4_(4,8,9) ST4_(5,10,11) ST4_(6,12,13) ST4_(7,14,15)
#undef ST4_
    }
    __syncthreads();

    // ---- P3: L2 wires 4..7 (bits 7..4, in-place) ----
    {
        const int B3 = slot_of((t & 15) | ((t >> 4) << 8)) << 3;
#define LD_B(j) { float2 v_ = *(const float2*)(stb + (B3 ^ (slot_of((j) << 4) << 3))); \
                  r##j = v_.x; u##j = v_.y; }
        FOR16(LD_B)
#undef LD_B
        APW8(4)
        APW4(5)
        APW2(6)
        APW1(7)
#define ST_B(j) *(float2*)(stb + (B3 ^ (slot_of((j) << 4) << 3))) = \
        make_float2(r##j, u##j);
        FOR16(ST_B)
#undef ST_B
    }
    __syncthreads();

    // ---- P4: L2 wires 0..3 + CNOT2 fold + readout (read-only) ----
    float local = 0.f;
    {
        const int B4 = slot_of(t) << 3;
#define LD_C(j) { float2 v_ = *(const float2*)(stb + (B4 ^ (slot_of((j) << 8) << 3))); \
                  r##j = v_.x; u##j = v_.y; }
        FOR16(LD_C)
#undef LD_C
        APW8(0)
        APW4(1)
        APW2(2)
        APW1(3)
        const int pt = px12(t);
#define RD(j) { int d_ = pt ^ px12((j) << 8); \
        local += (r##j * r##j + u##j * u##j) * (T1[d_ & 63] + T2[d_ >> 6]); }
        FOR16(RD)
#undef RD
    }

    // ---- block reduction ----
    #pragma unroll
    for (int off = 32; off > 0; off >>= 1)
        local += __shfl_down(local, off, 64);
    if ((t & 63) == 0) wsum[t >> 6] = local;
    __syncthreads();
    if (t == 0)
        out[b] = wsum[0] + wsum[1] + wsum[2] + wsum[3] + head_b[0];
}

extern "C" void kernel_launch(void* const* d_in, const int* in_sizes, int n_in,
                              void* d_out, int out_size, void* d_ws, size_t ws_size,
                              hipStream_t stream) {
    const float* x      = (const float*)d_in[0];
    const float* params = (const float*)d_in[1];
    const float* head_w = (const float*)d_in[2];
    const float* head_b = (const float*)d_in[3];
    float* out = (float*)d_out;
    const int B = in_sizes[0] / NW;   // 4096
    qsim_kernel<<<B, TPB, 0, stream>>>(x, params, head_w, head_b, out);
}

// Round 8
// 121.786 us; speedup vs baseline: 2.4707x; 1.0146x over previous
//
#include <hip/hip_runtime.h>
#include <math.h>

#define NW 12
#define DIM 4096
#define TPB 256

// Bank-conflict-reducing bijective slot map (XOR-linear involution, fixes bit 0).
__device__ __forceinline__ int slot_of(int i) {
    return i ^ ((((i >> 5) ^ (i >> 9)) & 15) << 1);
}
// Prefix-XOR (inverse Gray code): px12(j) ^ (px12(j)>>1) == j. XOR-linear.
__device__ __forceinline__ int px12(int j) {
    j ^= j >> 1; j ^= j >> 2; j ^= j >> 4; j ^= j >> 8;
    return j;
}

#define FOR16(X) X(0) X(1) X(2) X(3) X(4) X(5) X(6) X(7) \
                 X(8) X(9) X(10) X(11) X(12) X(13) X(14) X(15)

// (pr,pi) *= (fr,fi)
__device__ __forceinline__ void cmul(float& pr, float& pi, float fr, float fi) {
    float t0 = pi * fi, t1 = pi * fr;
    pi = fmaf(pr, fi, t1);
    pr = fmaf(pr, fr, -t0);
}

// fused U = RY(p2)*RX(p1)*RZ(p0); row-major complex 2x2 as 8 floats
struct GateU { float g0,g1,g2,g3,g4,g5,g6,g7; };
__device__ __forceinline__ GateU fuse_u(const float* p) {
    float s1,c1,s2,c2,s3,c3;
    sincosf(0.5f * p[0], &s1, &c1);   // RZ
    sincosf(0.5f * p[1], &s2, &c2);   // RX
    sincosf(0.5f * p[2], &s3, &c3);   // RY
    GateU r;
    r.g0 =  c3*c2*c1 + s3*s2*s1;
    r.g1 =  s3*s2*c1 - c3*c2*s1;
    r.g2 =  c3*s2*s1 - s3*c2*c1;
    r.g3 = -(c3*s2*c1 + s3*c2*s1);
    r.g4 =  s3*c2*c1 - c3*s2*s1;
    r.g5 = -(s3*c2*s1 + c3*s2*c1);
    r.g6 =  s3*s2*s1 + c3*c2*c1;
    r.g7 =  c3*c2*s1 - s3*s2*c1;
    return r;
}

// apply complex 2x2 gate (ga = row0, gb = row1) to one amplitude pair
__device__ __forceinline__ void gpair(const float4 ga, const float4 gb,
                                      float& ar, float& ai,
                                      float& br, float& bi) {
    float a0r = ar, a0i = ai, a1r = br, a1i = bi;
    ar = ga.x*a0r - ga.y*a0i + ga.z*a1r - ga.w*a1i;
    ai = ga.x*a0i + ga.y*a0r + ga.z*a1i + ga.w*a1r;
    br = gb.x*a0r - gb.y*a0i + gb.z*a1r - gb.w*a1i;
    bi = gb.x*a0i + gb.y*a0r + gb.z*a1i + gb.w*a1r;
}

// per-pass gate application on the 16-amp register subcube (mask 8/4/2/1)
#define APW8(W) { const float4 ga = gm4[2*(W)], gb = gm4[2*(W)+1]; \
    gpair(ga,gb,r0,u0,r8,u8);     gpair(ga,gb,r1,u1,r9,u9); \
    gpair(ga,gb,r2,u2,r10,u10);   gpair(ga,gb,r3,u3,r11,u11); \
    gpair(ga,gb,r4,u4,r12,u12);   gpair(ga,gb,r5,u5,r13,u13); \
    gpair(ga,gb,r6,u6,r14,u14);   gpair(ga,gb,r7,u7,r15,u15); }

#define APW4(W) { const float4 ga = gm4[2*(W)], gb = gm4[2*(W)+1]; \
    gpair(ga,gb,r0,u0,r4,u4);     gpair(ga,gb,r1,u1,r5,u5); \
    gpair(ga,gb,r2,u2,r6,u6);     gpair(ga,gb,r3,u3,r7,u7); \
    gpair(ga,gb,r8,u8,r12,u12);   gpair(ga,gb,r9,u9,r13,u13); \
    gpair(ga,gb,r10,u10,r14,u14); gpair(ga,gb,r11,u11,r15,u15); }

#define APW2(W) { const float4 ga = gm4[2*(W)], gb = gm4[2*(W)+1]; \
    gpair(ga,gb,r0,u0,r2,u2);     gpair(ga,gb,r1,u1,r3,u3); \
    gpair(ga,gb,r4,u4,r6,u6);     gpair(ga,gb,r5,u5,r7,u7); \
    gpair(ga,gb,r8,u8,r10,u10);   gpair(ga,gb,r9,u9,r11,u11); \
    gpair(ga,gb,r12,u12,r14,u14); gpair(ga,gb,r13,u13,r15,u15); }

#define APW1(W) { const float4 ga = gm4[2*(W)], gb = gm4[2*(W)+1]; \
    gpair(ga,gb,r0,u0,r1,u1);     gpair(ga,gb,r2,u2,r3,u3); \
    gpair(ga,gb,r4,u4,r5,u5);     gpair(ga,gb,r6,u6,r7,u7); \
    gpair(ga,gb,r8,u8,r9,u9);     gpair(ga,gb,r10,u10,r11,u11); \
    gpair(ga,gb,r12,u12,r13,u13); gpair(ga,gb,r14,u14,r15,u15); }

__global__ __launch_bounds__(TPB) void qsim_kernel(
    const float* __restrict__ x,        // (B, NW)
    const float* __restrict__ params,   // (NL, NW, 3)
    const float* __restrict__ head_w,   // (1, NW)
    const float* __restrict__ head_b,   // (1,)
    float* __restrict__ out)            // (B,)
{
    __shared__ float4 st4[DIM / 2];     // state, swizzled float2 slots (16B-aligned)
    __shared__ float2 ab[2 * NW];       // (alpha,beta) per wire: enc+L1 folded
    __shared__ float2 leaf2[32];        // parity-expanded leaf products (wires 8..11)
    __shared__ float4 gm4[2 * NW];      // L2 fused gates, 2 x float4 each
    __shared__ float T1[64], T2[64];    // readout sign-weighted tables
    __shared__ float wsum[TPB / 64];
    char* stb = (char*)st4;

    const int t = threadIdx.x;
    const int b = blockIdx.x;

    // ---------------- setup phase A (disjoint thread ranges) ----------------
    if (t < NW) {
        // wire t: fused L1 gate folded with encoding RY(x): (alpha,beta)=U*(c,s)
        GateU U = fuse_u(params + t * 3);             // layer 0
        float sx, cx; sincosf(0.5f * x[b * NW + t], &sx, &cx);
        ab[2*t]   = make_float2(U.g0*cx + U.g2*sx, U.g1*cx + U.g3*sx);
        ab[2*t+1] = make_float2(U.g4*cx + U.g6*sx, U.g5*cx + U.g7*sx);
    } else if (t < 2 * NW) {
        int w = t - NW;
        GateU U = fuse_u(params + (NW + w) * 3);      // layer 1
        gm4[2*w]   = make_float4(U.g0, U.g1, U.g2, U.g3);
        gm4[2*w+1] = make_float4(U.g4, U.g5, U.g6, U.g7);
    } else if (t >= 64 && t < 128) {
        int m = t - 64;               // bits 0..5 of final index -> wires 11..6
        float v = 0.f;
        #pragma unroll
        for (int w = 6; w < 12; ++w)
            v += ((m >> (11 - w)) & 1) ? -head_w[w] : head_w[w];
        T1[m] = v;
    } else if (t >= 128 && t < 192) {
        int m = t - 128;              // bits 6..11 of final index -> wires 5..0
        float v = 0.f;
        #pragma unroll
        for (int w = 0; w < 6; ++w)
            v += ((m >> (5 - w)) & 1) ? -head_w[w] : head_w[w];
        T2[m] = v;
    }
    __syncthreads();

    // ---- setup phase B: leaf2[p][m] = product over wires 8..11 for source
    //      low-nibble n = gray4(m) ^ (p<<3)  (parity-expanded leaf table) ----
    if (t < 32) {
        int p = t >> 4, m = t & 15;
        int n = (m ^ (m >> 1)) ^ (p << 3);
        float2 f8 = ab[16 + ((n >> 3) & 1)];
        float2 f9 = ab[18 + ((n >> 2) & 1)];
        float2 fA = ab[20 + ((n >> 1) & 1)];
        float2 fB = ab[22 + (n & 1)];
        float pr = f8.x, pi = f8.y;
        cmul(pr, pi, f9.x, f9.y);
        cmul(pr, pi, fA.x, fA.y);
        cmul(pr, pi, fB.x, fB.y);
        leaf2[t] = make_float2(pr, pi);
    }
    __syncthreads();

    float r0,r1,r2,r3,r4,r5,r6,r7,r8,r9,r10,r11,r12,r13,r14,r15;
    float u0,u1,u2,u3,u4,u5,u6,u7,u8,u9,u10,u11,u12,u13,u14,u15;

    // ---- P1 (fused): thread t builds DESTINATION block i = t*16+m of the
    //      post-L1, post-CNOT1 state directly in registers:
    //        src j = gray12(i): high byte = gray8(t), low nibble = gray4(m)^((t&1)<<3)
    //      then applies L2 wires 8..11 (bits 3..0) in-register, stores float4.
    {
        const int gt = (t ^ (t >> 1)) & 255;
        float2 f0 = ab[(gt >> 7) & 1];
        float Pr = f0.x, Pi = f0.y;
        #pragma unroll
        for (int w = 1; w < 8; ++w) {
            float2 g = ab[2 * w + ((gt >> (7 - w)) & 1)];
            cmul(Pr, Pi, g.x, g.y);
        }
        const float2* lf = leaf2 + ((t & 1) << 4);
#define MK(m) { float2 l_ = lf[m]; \
        float i0 = Pi * l_.y, i1 = Pi * l_.x; \
        r##m = fmaf(Pr, l_.x, -i0); u##m = fmaf(Pr, l_.y, i1); }
        FOR16(MK)
#undef MK
        APW8(8)
        APW4(9)
        APW2(10)
        APW1(11)
        const int B2 = slot_of(t << 4) << 3;          // 16B-aligned
#define ST4_(m, A, B) *(float4*)(stb + (B2 ^ ((m) << 4))) = \
        make_float4(r##A, u##A, r##B, u##B);
        ST4_(0,0,1) ST4_(1,2,3) ST4_(2,4,5) ST4_(3,6,7)
        ST4_(4,8,9) ST4_(5,10,11) ST4_(6,12,13) ST4_(7,14,15)
#undef ST4_
    }
    __syncthreads();

    // ---- P2: L2 wires 4..7 (bits 7..4, in-place) ----
    {
        const int B3 = slot_of((t & 15) | ((t >> 4) << 8)) << 3;
#define LD_B(j) { float2 v_ = *(const float2*)(stb + (B3 ^ (slot_of((j) << 4) << 3))); \
                  r##j = v_.x; u##j = v_.y; }
        FOR16(LD_B)
#undef LD_B
        APW8(4)
        APW4(5)
        APW2(6)
        APW1(7)
#define ST_B(j) *(float2*)(stb + (B3 ^ (slot_of((j) << 4) << 3))) = \
        make_float2(r##j, u##j);
        FOR16(ST_B)
#undef ST_B
    }
    __syncthreads();

    // ---- P3: L2 wires 0..3 + CNOT2 fold + readout (read-only) ----
    float local = 0.f;
    {
        const int B4 = slot_of(t) << 3;
#define LD_C(j) { float2 v_ = *(const float2*)(stb + (B4 ^ (slot_of((j) << 8) << 3))); \
                  r##j = v_.x; u##j = v_.y; }
        FOR16(LD_C)
#undef LD_C
        APW8(0)
        APW4(1)
        APW2(2)
        APW1(3)
        const int pt = px12(t);
#define RD(j) { int d_ = pt ^ px12((j) << 8); \
        local += (r##j * r##j + u##j * u##j) * (T1[d_ & 63] + T2[d_ >> 6]); }
        FOR16(RD)
#undef RD
    }

    // ---- block reduction ----
    #pragma unroll
    for (int off = 32; off > 0; off >>= 1)
        local += __shfl_down(local, off, 64);
    if ((t & 63) == 0) wsum[t >> 6] = local;
    __syncthreads();
    if (t == 0)
        out[b] = wsum[0] + wsum[1] + wsum[2] + wsum[3] + head_b[0];
}

extern "C" void kernel_launch(void* const* d_in, const int* in_sizes, int n_in,
                              void* d_out, int out_size, void* d_ws, size_t ws_size,
                              hipStream_t stream) {
    const float* x      = (const float*)d_in[0];
    const float* params = (const float*)d_in[1];
    const float* head_w = (const float*)d_in[2];
    const float* head_b = (const float*)d_in[3];
    float* out = (float*)d_out;
    const int B = in_sizes[0] / NW;   // 4096
    qsim_kernel<<<B, TPB, 0, stream>>>(x, params, head_w, head_b, out);
}

// Round 10
// 63.133 us; speedup vs baseline: 4.7662x; 1.9290x over previous
//
#include <hip/hip_runtime.h>
#include <math.h>

#define NW 12
#define TPB 64

// fused U = RY(p2)*RX(p1)*RZ(p0); row-major complex 2x2 as 8 floats
// SU(2): row0 = (a, b) = (g0+ig1, g2+ig3); row1 = (-conj(b), conj(a)).
struct GateU { float g0,g1,g2,g3,g4,g5,g6,g7; };
__device__ __forceinline__ GateU fuse_u(const float* p) {
    float s1,c1,s2,c2,s3,c3;
    sincosf(0.5f * p[0], &s1, &c1);   // RZ
    sincosf(0.5f * p[1], &s2, &c2);   // RX
    sincosf(0.5f * p[2], &s3, &c3);   // RY
    GateU r;
    r.g0 =  c3*c2*c1 + s3*s2*s1;
    r.g1 =  s3*s2*c1 - c3*c2*s1;
    r.g2 =  c3*s2*s1 - s3*c2*c1;
    r.g3 = -(c3*s2*c1 + s3*c2*s1);
    r.g4 =  s3*c2*c1 - c3*s2*s1;
    r.g5 = -(s3*c2*s1 + c3*s2*c1);
    r.g6 =  s3*s2*s1 + c3*c2*c1;
    r.g7 =  c3*c2*s1 - s3*s2*c1;
    return r;
}

// Transfer-matrix contraction of the 12-wire circuit.
//   v_j = U1_j * (cos x_j/2, sin x_j/2)            (encoding + layer-1 folded)
//   phi_n = prod_j v_j(n_j ^ n_{j-1})              (CNOT chain 1 = gray map)
//   feats_w = <phi| (x)_{j<=w} M_j |phi>,  M_j = V_j^dag Z V_j   (CNOT chain 2
//   turns Z_w into Z_0..Z_w; layer-2 V conjugates it to a product operator)
// Forward Hermitian message F (F00,F11 real; F01 complex), backward real h.
__global__ __launch_bounds__(TPB) void qsim_kernel(
    const float* __restrict__ x,        // (B, NW)
    const float* __restrict__ params,   // (2, NW, 3)
    const float* __restrict__ head_w,   // (1, NW)
    const float* __restrict__ head_b,   // (1,)
    float* __restrict__ out,            // (B,)
    int Bn)
{
    __shared__ float U1[NW][8];   // layer-1 fused gates
    __shared__ float Mg[NW][3];   // M_j: d, c_r, c_i
    __shared__ float hw[NW];
    __shared__ float hb;

    const int t = threadIdx.x;

    if (t < NW) {
        GateU U = fuse_u(params + t * 3);
        U1[t][0]=U.g0; U1[t][1]=U.g1; U1[t][2]=U.g2; U1[t][3]=U.g3;
        U1[t][4]=U.g4; U1[t][5]=U.g5; U1[t][6]=U.g6; U1[t][7]=U.g7;
        hw[t] = head_w[t];
    } else if (t < 2 * NW) {
        int w = t - NW;
        GateU V = fuse_u(params + (NW + w) * 3);
        float ar=V.g0, ai=V.g1, br=V.g2, bi=V.g3;     // a, b of SU(2)
        Mg[w][0] = (ar*ar + ai*ai) - (br*br + bi*bi); // d  = |a|^2-|b|^2
        Mg[w][1] = 2.f*(ar*br + ai*bi);               // c_r, c = 2*conj(a)*b
        Mg[w][2] = 2.f*(ar*bi - ai*br);               // c_i
    } else if (t == 2 * NW) {
        hb = head_b[0];
    }
    __syncthreads();

    const int s = blockIdx.x * TPB + t;
    if (s >= Bn) return;

    // ---- per-wire vectors v_j (encoding RY folded through layer-1 gate) ----
    float v0r[NW], v0i[NW], v1r[NW], v1i[NW];
    const float* xs = x + s * NW;
    #pragma unroll
    for (int j = 0; j < NW; ++j) {
        float sx, cx; sincosf(0.5f * xs[j], &sx, &cx);
        v0r[j] = U1[j][0]*cx + U1[j][2]*sx;
        v0i[j] = U1[j][1]*cx + U1[j][3]*sx;
        v1r[j] = U1[j][4]*cx + U1[j][6]*sx;
        v1i[j] = U1[j][5]*cx + U1[j][7]*sx;
    }

    // ---- backward pass: h[j][b] (identity wires j..11), h[12] = {1,1} ----
    float h[NW + 1][2];
    h[NW][0] = 1.f; h[NW][1] = 1.f;
    #pragma unroll
    for (int j = NW - 1; j >= 1; --j) {
        float p0 = v0r[j]*v0r[j] + v0i[j]*v0i[j];
        float p1 = v1r[j]*v1r[j] + v1i[j]*v1i[j];
        h[j][0] = p0 * h[j+1][0] + p1 * h[j+1][1];
        h[j][1] = p1 * h[j+1][0] + p0 * h[j+1][1];
    }

    // ---- forward pass: F_j = conj(M_j) o (A_j F_{j-1} A_j^dag) ----
    float F00 = 0.f, F11 = 0.f, F01r = 0.f, F01i = 0.f, acc = 0.f;
    #pragma unroll
    for (int j = 0; j < NW; ++j) {
        float vr = v0r[j], vi = v0i[j], wr = v1r[j], wi = v1i[j];
        float S00, S11, S01r, S01i;
        if (j == 0) {
            S00  = vr*vr + vi*vi;
            S11  = wr*wr + wi*wi;
            S01r = vr*wr + vi*wi;          // v(0) * conj(v(1))
            S01i = vi*wr - vr*wi;
        } else {
            // T = F * A^dag,  A = [[v,w],[w,v]] symmetric
            float T00r =  F00*vr + (F01r*wr + F01i*wi);
            float T00i = -F00*vi + (F01i*wr - F01r*wi);
            float T01r =  F00*wr + (F01r*vr + F01i*vi);
            float T01i = -F00*wi + (F01i*vr - F01r*vi);
            float T10r = (F01r*vr - F01i*vi) + F11*wr;
            float T10i = -(F01r*vi + F01i*vr) - F11*wi;
            float T11r = (F01r*wr - F01i*wi) + F11*vr;
            float T11i = -(F01r*wi + F01i*wr) - F11*vi;
            // S = A * T   (S Hermitian: S00,S11 real)
            S00  = vr*T00r - vi*T00i + wr*T10r - wi*T10i;
            S11  = wr*T01r - wi*T01i + vr*T11r - vi*T11i;
            S01r = vr*T01r - vi*T01i + wr*T11r - wi*T11i;
            S01i = vr*T01i + vi*T01r + wr*T11i + wi*T11r;
        }
        float d = Mg[j][0], cr = Mg[j][1], ci = Mg[j][2];
        F00  =  d * S00;
        F11  = -d * S11;
        F01r =  cr*S01r + ci*S01i;         // conj(c) * S01
        F01i =  cr*S01i - ci*S01r;

        // contract with backward part G_{j+1}
        float G00, G11, G01r, G01i;
        if (j < NW - 1) {
            G00 = h[j+1][0]; G11 = h[j+1][1];
            float qr = v0r[j+1]*v1r[j+1] + v0i[j+1]*v1i[j+1];  // v(0)conj(v(1))
            float qi = v0i[j+1]*v1r[j+1] - v0r[j+1]*v1i[j+1];
            G01r = qr * (h[j+2][0] + h[j+2][1]);
            G01i = qi * (h[j+2][0] - h[j+2][1]);
        } else {
            G00 = 1.f; G11 = 1.f; G01r = 1.f; G01i = 0.f;      // all-ones boundary
        }
        float feat = F00*G00 + F11*G11 + 2.f*(F01r*G01r - F01i*G01i);
        acc += hw[j] * feat;
    }

    out[s] = acc + hb;
}

extern "C" void kernel_launch(void* const* d_in, const int* in_sizes, int n_in,
                              void* d_out, int out_size, void* d_ws, size_t ws_size,
                              hipStream_t stream) {
    const float* x      = (const float*)d_in[0];
    const float* params = (const float*)d_in[1];
    const float* head_w = (const float*)d_in[2];
    const float* head_b = (const float*)d_in[3];
    float* out = (float*)d_out;
    const int B = in_sizes[0] / NW;               // 4096
    const int grid = (B + TPB - 1) / TPB;         // 64 blocks x 64 threads
    qsim_kernel<<<grid, TPB, 0, stream>>>(x, params, head_w, head_b, out, B);
}

// Round 11
// 61.025 us; speedup vs baseline: 4.9307x; 1.0345x over previous
//
#include <hip/hip_runtime.h>
#include <math.h>

#define NW 12
#define TPB 64

// Hardware sin/cos of (a) radians via v_sin_f32/v_cos_f32 (input: revolutions).
// Valid & accurate for |a| < ~100 rad; inputs here are |x|/2 < ~3 rad.
__device__ __forceinline__ void hw_sincos(float a, float* s, float* c) {
    const float INV2PI = 0.15915494309189535f;
    float r = a * INV2PI;
    *s = __builtin_amdgcn_sinf(r);
    *c = __builtin_amdgcn_cosf(r);
}

// fused U = RY(p2)*RX(p1)*RZ(p0); row-major complex 2x2 as 8 floats
// SU(2): row0 = (a, b) = (g0+ig1, g2+ig3); row1 = (-conj(b), conj(a)).
struct GateU { float g0,g1,g2,g3,g4,g5,g6,g7; };
__device__ __forceinline__ GateU fuse_u(const float* p) {
    float s1,c1,s2,c2,s3,c3;
    hw_sincos(0.5f * p[0], &s1, &c1);   // RZ
    hw_sincos(0.5f * p[1], &s2, &c2);   // RX
    hw_sincos(0.5f * p[2], &s3, &c3);   // RY
    GateU r;
    r.g0 =  c3*c2*c1 + s3*s2*s1;
    r.g1 =  s3*s2*c1 - c3*c2*s1;
    r.g2 =  c3*s2*s1 - s3*c2*c1;
    r.g3 = -(c3*s2*c1 + s3*c2*s1);
    r.g4 =  s3*c2*c1 - c3*s2*s1;
    r.g5 = -(s3*c2*s1 + c3*s2*c1);
    r.g6 =  s3*s2*s1 + c3*c2*c1;
    r.g7 =  c3*c2*s1 - s3*s2*c1;
    return r;
}

// Transfer-matrix contraction of the 12-wire circuit.
//   v_j = U1_j * (cos x_j/2, sin x_j/2)            (encoding + layer-1 folded)
//   phi_n = prod_j v_j(n_j ^ n_{j-1})              (CNOT chain 1 = gray map)
//   feats_w = <phi| (x)_{j<=w} M_j |phi>,  M_j = V_j^dag Z V_j   (CNOT chain 2
//   turns Z_w into Z_0..Z_w; layer-2 V conjugates it to a product operator)
// Forward Hermitian message F (F00,F11 real; F01 complex), backward real h.
__global__ __launch_bounds__(TPB) void qsim_kernel(
    const float* __restrict__ x,        // (B, NW)
    const float* __restrict__ params,   // (2, NW, 3)
    const float* __restrict__ head_w,   // (1, NW)
    const float* __restrict__ head_b,   // (1,)
    float* __restrict__ out,            // (B,)
    int Bn)
{
    __shared__ float U1[NW][8];   // layer-1 fused gates
    __shared__ float Mg[NW][3];   // M_j: d, c_r, c_i
    __shared__ float hw[NW];
    __shared__ float hb;

    const int t = threadIdx.x;

    if (t < NW) {
        GateU U = fuse_u(params + t * 3);
        U1[t][0]=U.g0; U1[t][1]=U.g1; U1[t][2]=U.g2; U1[t][3]=U.g3;
        U1[t][4]=U.g4; U1[t][5]=U.g5; U1[t][6]=U.g6; U1[t][7]=U.g7;
        hw[t] = head_w[t];
    } else if (t < 2 * NW) {
        int w = t - NW;
        GateU V = fuse_u(params + (NW + w) * 3);
        float ar=V.g0, ai=V.g1, br=V.g2, bi=V.g3;     // a, b of SU(2)
        Mg[w][0] = (ar*ar + ai*ai) - (br*br + bi*bi); // d  = |a|^2-|b|^2
        Mg[w][1] = 2.f*(ar*br + ai*bi);               // c_r, c = 2*conj(a)*b
        Mg[w][2] = 2.f*(ar*bi - ai*br);               // c_i
    } else if (t == 2 * NW) {
        hb = head_b[0];
    }
    __syncthreads();

    const int s = blockIdx.x * TPB + t;
    if (s >= Bn) return;

    // ---- per-wire vectors v_j (encoding RY folded through layer-1 gate) ----
    float v0r[NW], v0i[NW], v1r[NW], v1i[NW];
    const float* xs = x + s * NW;
    #pragma unroll
    for (int j = 0; j < NW; ++j) {
        float sx, cx; hw_sincos(0.5f * xs[j], &sx, &cx);
        v0r[j] = U1[j][0]*cx + U1[j][2]*sx;
        v0i[j] = U1[j][1]*cx + U1[j][3]*sx;
        v1r[j] = U1[j][4]*cx + U1[j][6]*sx;
        v1i[j] = U1[j][5]*cx + U1[j][7]*sx;
    }

    // ---- backward pass: h[j][b] (identity wires j..11), h[12] = {1,1} ----
    float h[NW + 1][2];
    h[NW][0] = 1.f; h[NW][1] = 1.f;
    #pragma unroll
    for (int j = NW - 1; j >= 1; --j) {
        float p0 = v0r[j]*v0r[j] + v0i[j]*v0i[j];
        float p1 = v1r[j]*v1r[j] + v1i[j]*v1i[j];
        h[j][0] = p0 * h[j+1][0] + p1 * h[j+1][1];
        h[j][1] = p1 * h[j+1][0] + p0 * h[j+1][1];
    }

    // ---- forward pass: F_j = conj(M_j) o (A_j F_{j-1} A_j^dag) ----
    float F00 = 0.f, F11 = 0.f, F01r = 0.f, F01i = 0.f, acc = 0.f;
    #pragma unroll
    for (int j = 0; j < NW; ++j) {
        float vr = v0r[j], vi = v0i[j], wr = v1r[j], wi = v1i[j];
        float S00, S11, S01r, S01i;
        if (j == 0) {
            S00  = vr*vr + vi*vi;
            S11  = wr*wr + wi*wi;
            S01r = vr*wr + vi*wi;          // v(0) * conj(v(1))
            S01i = vi*wr - vr*wi;
        } else {
            // T = F * A^dag,  A = [[v,w],[w,v]] symmetric
            float T00r =  F00*vr + (F01r*wr + F01i*wi);
            float T00i = -F00*vi + (F01i*wr - F01r*wi);
            float T01r =  F00*wr + (F01r*vr + F01i*vi);
            float T01i = -F00*wi + (F01i*vr - F01r*vi);
            float T10r = (F01r*vr - F01i*vi) + F11*wr;
            float T10i = -(F01r*vi + F01i*vr) - F11*wi;
            float T11r = (F01r*wr - F01i*wi) + F11*vr;
            float T11i = -(F01r*wi + F01i*wr) - F11*vi;
            // S = A * T   (S Hermitian: S00,S11 real)
            S00  = vr*T00r - vi*T00i + wr*T10r - wi*T10i;
            S11  = wr*T01r - wi*T01i + vr*T11r - vi*T11i;
            S01r = vr*T01r - vi*T01i + wr*T11r - wi*T11i;
            S01i = vr*T01i + vi*T01r + wr*T11i + wi*T11r;
        }
        float d = Mg[j][0], cr = Mg[j][1], ci = Mg[j][2];
        F00  =  d * S00;
        F11  = -d * S11;
        F01r =  cr*S01r + ci*S01i;         // conj(c) * S01
        F01i =  cr*S01i - ci*S01r;

        // contract with backward part G_{j+1}
        float G00, G11, G01r, G01i;
        if (j < NW - 1) {
            G00 = h[j+1][0]; G11 = h[j+1][1];
            float qr = v0r[j+1]*v1r[j+1] + v0i[j+1]*v1i[j+1];  // v(0)conj(v(1))
            float qi = v0i[j+1]*v1r[j+1] - v0r[j+1]*v1i[j+1];
            G01r = qr * (h[j+2][0] + h[j+2][1]);
            G01i = qi * (h[j+2][0] - h[j+2][1]);
        } else {
            G00 = 1.f; G11 = 1.f; G01r = 1.f; G01i = 0.f;      // all-ones boundary
        }
        float feat = F00*G00 + F11*G11 + 2.f*(F01r*G01r - F01i*G01i);
        acc += hw[j] * feat;
    }

    out[s] = acc + hb;
}

extern "C" void kernel_launch(void* const* d_in, const int* in_sizes, int n_in,
                              void* d_out, int out_size, void* d_ws, size_t ws_size,
                              hipStream_t stream) {
    const float* x      = (const float*)d_in[0];
    const float* params = (const float*)d_in[1];
    const float* head_w = (const float*)d_in[2];
    const float* head_b = (const float*)d_in[3];
    float* out = (float*)d_out;
    const int B = in_sizes[0] / NW;               // 4096
    const int grid = (B + TPB - 1) / TPB;         // 64 blocks x 64 threads
    qsim_kernel<<<grid, TPB, 0, stream>>>(x, params, head_w, head_b, out, B);
}